// Round 1
// 1672.584 us; speedup vs baseline: 1.2540x; 1.2540x over previous
//
#include <hip/hip_runtime.h>

#define D_MODEL 1024
#define NH      16
#define DHEAD   64
#define DFF     4096
#define BATCH   4
#define SEQ     1024
#define NLAYER  6
#define MTOT    (BATCH*SEQ)   // 4096 rows

typedef _Float16 half8 __attribute__((ext_vector_type(8)));
typedef _Float16 half4v __attribute__((ext_vector_type(4)));
typedef float   floatx4 __attribute__((ext_vector_type(4)));

static __device__ __forceinline__ floatx4 mfma16(half8 a, half8 b, floatx4 c) {
    return __builtin_amdgcn_mfma_f32_16x16x32_f16(a, b, c, 0, 0, 0);
}

// async global->LDS, 16B per lane; lds dst must be wave-uniform (lane*16B auto)
static __device__ __forceinline__ void gl_lds16(const _Float16* g, _Float16* l) {
    __builtin_amdgcn_global_load_lds(
        (const __attribute__((address_space(1))) _Float16*)g,
        (__attribute__((address_space(3))) _Float16*)l, 16, 0, 0);
}

// counted vmem wait (NEVER vmcnt(0) in the GEMM main loop) — memory clobber
// keeps the compiler from moving loads/intrinsics across it.
#define VMCNT(n) asm volatile("s_waitcnt vmcnt(" #n ")" ::: "memory")

// ---------------------------------------------------------------- pos encode
__global__ __launch_bounds__(256) void posenc_kernel(
        const float* __restrict__ xin, float* __restrict__ xf,
        _Float16* __restrict__ xh) {
    const int row = blockIdx.x;            // b*S + s
    const int s = row & (SEQ - 1);
    const float neg_log_inc = -9.210340371976184f / 511.0f;  // -ln(1e4)/(nt-1)
#pragma unroll
    for (int i = 0; i < 4; ++i) {
        const int d = threadIdx.x + i * 256;
        const int j = d & 511;
        const float inv = expf((float)j * neg_log_inc);
        const float arg = (float)s * inv;
        const float sig = (d < 512) ? sinf(arg) : cosf(arg);
        const float v = xin[(size_t)row * D_MODEL + d] + sig;
        xf[(size_t)row * D_MODEL + d] = v;
        xh[(size_t)row * D_MODEL + d] = (_Float16)v;
    }
}

// ------------------------------------------------- weight transpose + cvt f16
__global__ __launch_bounds__(256) void transpose_cvt_kernel(
        const float* __restrict__ src, _Float16* __restrict__ dst, int R, int C) {
    __shared__ float tile[32][33];
    const size_t zoff = (size_t)blockIdx.z * R * C;
    src += zoff; dst += zoff;
    const int cb = blockIdx.x * 32, rb = blockIdx.y * 32;
    const int tx = threadIdx.x & 31, ty = threadIdx.x >> 5;
#pragma unroll
    for (int i = 0; i < 4; ++i)
        tile[ty + i * 8][tx] = src[(size_t)(rb + ty + i * 8) * C + cb + tx];
    __syncthreads();
#pragma unroll
    for (int i = 0; i < 4; ++i)
        dst[(size_t)(cb + ty + i * 8) * R + rb + tx] = (_Float16)tile[tx][ty + i * 8];
}

__global__ __launch_bounds__(256) void transpose_qkv_kernel(
        const float* __restrict__ Wq, const float* __restrict__ Wk,
        const float* __restrict__ Wv, int layer, _Float16* __restrict__ dst) {
    __shared__ float tile[32][33];
    const int z = blockIdx.z;
    const float* src = (z == 0 ? Wq : (z == 1 ? Wk : Wv))
                       + (size_t)layer * D_MODEL * D_MODEL;
    _Float16* dz = dst + (size_t)z * D_MODEL * D_MODEL;
    const int cb = blockIdx.x * 32, rb = blockIdx.y * 32;
    const int tx = threadIdx.x & 31, ty = threadIdx.x >> 5;
#pragma unroll
    for (int i = 0; i < 4; ++i)
        tile[ty + i * 8][tx] = src[(size_t)(rb + ty + i * 8) * D_MODEL + cb + tx];
    __syncthreads();
#pragma unroll
    for (int i = 0; i < 4; ++i)
        dz[(size_t)(cb + ty + i * 8) * D_MODEL + rb + tx] = (_Float16)tile[tx][ty + i * 8];
}

// ---------------------------------------------------------------- NT GEMM 256²
// 256x256 tile, 8 waves (2M x 4N), BK=32, 4 LDS buffers (128 KiB), depth-3
// prefetch with counted vmcnt (T3+T4), raw s_barrier (1 per K-tile), setprio
// around the MFMA cluster (T5). Conflict-free chunked-k LDS layout
// [buf][kchunk][row][8] (proven 0-conflict in the 128² predecessor).
//
// Pipeline invariants (per wave, 4 loads per issue()):
//   entering tile t: tiles <= t landed for ALL waves (prev vmcnt(8)+barrier);
//   issue(t+3) overwrites buf((t-1)&3) -- all waves finished reading tile t-1
//   before the barrier that precedes this issue;
//   end of tile t: vmcnt(8) leaves exactly tiles t+2,t+3 in flight -> t+1
//   landed; barrier publishes it to all waves.
//
// MODE 0: qkv fused; q,k -> outp (scaled q), v -> outp2 as vT[b][h][dh][s]
// MODE 2: relu(+bias0), f16 out [M][N]
// MODE 3: split-K raw f16 partial out at outp + z*M*N (bias added in LN)
template<int MODE, int SPLIT>
__global__ __launch_bounds__(512, 2) void gemm256_kernel(
        const _Float16* __restrict__ A, const _Float16* __restrict__ BT,
        const float* __restrict__ bias0, const float* __restrict__ bias1,
        const float* __restrict__ bias2, void* __restrict__ outp,
        void* __restrict__ outp2, int M, int N, int K) {
    __shared__ alignas(16) _Float16 a_s[4][4][256][8];   // [buf][k>>3][m][k&7]
    __shared__ alignas(16) _Float16 b_s[4][4][256][8];

    // ---- XCD-locality swizzle (requires (gridDim.y*gridDim.z)%8==0)
    const int l = blockIdx.x + gridDim.x * (blockIdx.y + gridDim.y * blockIdx.z);
    const int xcd = l & 7, j = l >> 3;
    const int bx = j % gridDim.x;
    const int g = xcd + 8 * (j / gridDim.x);
    const int bz = g % gridDim.z;
    const int by = g / gridDim.z;

    const int t = threadIdx.x;
    const int wv = t >> 6, lane = t & 63, quad = lane >> 4, lm = lane & 15;
    const int wm = wv >> 2, wn = wv & 3;            // wave tile: rows wm*128, cols wn*64
    const int mb = by * 256, nb = bx * 256;

    const int Keff = K / SPLIT;
    const int k0 = (SPLIT > 1) ? bz * Keff : 0;

    // staging role: waves 0-3 stage A k-chunks 0-3, waves 4-7 stage B chunks 0-3
    const int sop = wv >> 2, chunk = wv & 3;
    const _Float16* gbase = (sop ? (BT + (size_t)(nb + lane) * K)
                                 : (A + (size_t)(mb + lane) * K))
                            + k0 + (chunk << 3);
    _Float16* sb0 = sop ? &b_s[0][chunk][0][0] : &a_s[0][chunk][0][0];
    const size_t rstep = (size_t)64 * K;

    auto issue = [&](int tt) {
        const _Float16* gp = gbase + tt * 32;
        _Float16* dp = sb0 + (size_t)(tt & 3) * 8192;   // buf stride 4*256*8 halves
#pragma unroll
        for (int rg = 0; rg < 4; ++rg)
            gl_lds16(gp + rg * rstep, dp + rg * 512);   // 64 rows per load
    };

    floatx4 acc[8][4];
#pragma unroll
    for (int i = 0; i < 8; ++i)
#pragma unroll
        for (int jj = 0; jj < 4; ++jj) acc[i][jj] = (floatx4){0.f, 0.f, 0.f, 0.f};

    auto compute = [&](int buf) {
        half8 bfr[4];
#pragma unroll
        for (int nf = 0; nf < 4; ++nf)
            bfr[nf] = *(const half8*)&b_s[buf][quad][wn * 64 + nf * 16 + lm][0];
        __builtin_amdgcn_s_setprio(1);
#pragma unroll
        for (int mf = 0; mf < 8; ++mf) {
            const half8 am = *(const half8*)&a_s[buf][quad][wm * 128 + mf * 16 + lm][0];
#pragma unroll
            for (int nf = 0; nf < 4; ++nf)
                acc[mf][nf] = mfma16(am, bfr[nf], acc[mf][nf]);
        }
        __builtin_amdgcn_s_setprio(0);
    };

    const int NT = Keff >> 5;                 // >= 8 in all launches
    issue(0); issue(1); issue(2);
    VMCNT(8);                                 // tile 0 landed; 1,2 in flight
    __builtin_amdgcn_s_barrier();
    __builtin_amdgcn_sched_barrier(0);

    for (int tt = 0; tt < NT - 3; ++tt) {
        issue(tt + 3);                        // buf((tt-1)&3): retired last iter
        compute(tt & 3);
        VMCNT(8);                             // t+1 landed; t+2,t+3 in flight
        __builtin_amdgcn_s_barrier();
        __builtin_amdgcn_sched_barrier(0);
    }
    compute((NT - 3) & 3);
    VMCNT(4);                                 // NT-2 landed; NT-1 in flight
    __builtin_amdgcn_s_barrier();
    __builtin_amdgcn_sched_barrier(0);
    compute((NT - 2) & 3);
    VMCNT(0);                                 // NT-1 landed (tail only)
    __builtin_amdgcn_s_barrier();
    __builtin_amdgcn_sched_barrier(0);
    compute((NT - 1) & 3);

    // ------------------------------------------------------------- epilogue
#pragma unroll
    for (int mf = 0; mf < 8; ++mf) {
#pragma unroll
        for (int nf = 0; nf < 4; ++nf) {
            const int row0 = mb + wm * 128 + mf * 16 + quad * 4;
            const int col = nb + wn * 64 + nf * 16 + lm;
            if (MODE == 0 && (col >> 10) == 2) {
                // v -> vT[b][h][dh][s]; 4 r-values are 4 consecutive s
                const int nn = col & 1023, h = nn >> 6, dh = nn & 63;
                const int b = row0 >> 10, s0 = row0 & 1023;
                const float bias = bias2[nn];
                half4v v4;
#pragma unroll
                for (int r = 0; r < 4; ++r) v4[r] = (_Float16)(acc[mf][nf][r] + bias);
                *(half4v*)&((_Float16*)outp2)[
                    (size_t)((b * NH + h) * DHEAD + dh) * SEQ + s0] = v4;
                continue;
            }
#pragma unroll
            for (int r = 0; r < 4; ++r) {
                float v = acc[mf][nf][r];
                const int row = row0 + r;
                if (MODE == 0) {
                    const int sel = col >> 10, nn = col & 1023;
                    v += (sel == 0 ? bias0 : bias1)[nn];
                    if (sel == 0) v *= 0.125f;     // DH^-0.5
                    ((_Float16*)outp)[(size_t)sel * MTOT * D_MODEL +
                                      (size_t)row * D_MODEL + nn] = (_Float16)v;
                } else if (MODE == 2) {
                    v = fmaxf(v + bias0[col], 0.f);
                    ((_Float16*)outp)[(size_t)row * N + col] = (_Float16)v;
                } else {   // MODE 3: raw f16 partial
                    ((_Float16*)outp)[(size_t)bz * M * N +
                                      (size_t)row * N + col] = (_Float16)v;
                }
            }
        }
    }
}

// ------------------------------------------------------------ flash attention
// block = (b,h) x 64 q-rows; wave w owns q-rows q0+w*16..+15, all keys.
__global__ __launch_bounds__(256) void attn_kernel(
        const _Float16* __restrict__ q, const _Float16* __restrict__ k,
        const _Float16* __restrict__ vT, _Float16* __restrict__ o,
        const float* __restrict__ mask) {
    const int b = blockIdx.y >> 4, h = blockIdx.y & 15;
    const int q0 = blockIdx.x * 64;
    const int t = threadIdx.x;
    const int wv = t >> 6, lane = t & 63, quad = lane >> 4, lm = lane & 15;

    __shared__ alignas(16) _Float16 k_s[512 * 8];
    __shared__ alignas(16) _Float16 v_s[512 * 8];
    __shared__ alignas(16) _Float16 p_s[4][16][72];

    const _Float16* kb = k + (size_t)b * SEQ * D_MODEL + h * 64;
    const _Float16* vb = vT + (size_t)(b * NH + h) * DHEAD * SEQ;
    int koff[2], voff[2];
#pragma unroll
    for (int jj = 0; jj < 2; ++jj) {
        const int c = t + jj * 256;
        const int row = c >> 3, gg = (c & 7) ^ (row & 7);
        koff[jj] = row * D_MODEL + gg * 8;
        voff[jj] = row * SEQ + gg * 8;
    }
    _Float16* kdst0 = k_s + (size_t)(wv * 64) * 8;
    _Float16* kdst1 = kdst0 + 256 * 8;
    _Float16* vdst0 = v_s + (size_t)(wv * 64) * 8;
    _Float16* vdst1 = vdst0 + 256 * 8;

    half8 qf[2];
    {
        const size_t qrow = (size_t)(b * SEQ + q0 + wv * 16 + lm);
#pragma unroll
        for (int ks = 0; ks < 2; ++ks)
            qf[ks] = *(const half8*)(q + qrow * D_MODEL + h * 64 + ks * 32 + quad * 8);
    }

    float l_part[4] = {0.f, 0.f, 0.f, 0.f};
    floatx4 Oacc[4];
#pragma unroll
    for (int nt = 0; nt < 4; ++nt) Oacc[nt] = (floatx4){0.f, 0.f, 0.f, 0.f};

    for (int jb = 0; jb < 16; ++jb) {
        const int kk0 = jb * 64;
        __syncthreads();
        gl_lds16(kb + kk0 * D_MODEL + koff[0], kdst0);
        gl_lds16(kb + kk0 * D_MODEL + koff[1], kdst1);
        gl_lds16(vb + kk0 + voff[0], vdst0);
        gl_lds16(vb + kk0 + voff[1], vdst1);
        __syncthreads();

        floatx4 sacc[4];
#pragma unroll
        for (int nt = 0; nt < 4; ++nt) {
            sacc[nt] = (floatx4){0.f, 0.f, 0.f, 0.f};
            const int row = nt * 16 + lm;
#pragma unroll
            for (int ks = 0; ks < 2; ++ks) {
                const int gg = (ks * 4 + quad) ^ (lm & 7);
                const half8 kf = *(const half8*)&k_s[row * 64 + gg * 8];
                sacc[nt] = mfma16(qf[ks], kf, sacc[nt]);
            }
        }
#pragma unroll
        for (int nt = 0; nt < 4; ++nt) {
            const float madd = (1.0f - mask[b * SEQ + kk0 + nt * 16 + lm]) * (-1.0e8f);
#pragma unroll
            for (int r = 0; r < 4; ++r) {
                const float p = __expf(sacc[nt][r] + madd);
                l_part[r] += p;
                p_s[wv][quad * 4 + r][nt * 16 + lm] = (_Float16)p;
            }
        }
#pragma unroll
        for (int ks = 0; ks < 2; ++ks) {
            const half8 pf = *(const half8*)&p_s[wv][lm][ks * 32 + quad * 8];
#pragma unroll
            for (int nt = 0; nt < 4; ++nt) {
                const int row = nt * 16 + lm;
                const int gg = (ks * 4 + quad) ^ (lm & 7);
                const half8 vf = *(const half8*)&v_s[row * 64 + gg * 8];
                Oacc[nt] = mfma16(pf, vf, Oacc[nt]);
            }
        }
    }
#pragma unroll
    for (int r = 0; r < 4; ++r) {
        float v = l_part[r];
#pragma unroll
        for (int off = 1; off < 16; off <<= 1) v += __shfl_xor(v, off, 64);
        l_part[r] = 1.0f / v;
    }
#pragma unroll
    for (int nt = 0; nt < 4; ++nt)
#pragma unroll
        for (int r = 0; r < 4; ++r) {
            const float v = Oacc[nt][r] * l_part[r];
            o[(size_t)(b * SEQ + q0 + wv * 16 + quad * 4 + r) * D_MODEL +
              h * 64 + nt * 16 + lm] = (_Float16)v;
        }
}

// --------------------------------------- residual + split-K reduce + bias + LN
template<int SPLIT>
__global__ __launch_bounds__(256) void ln_fused_kernel(
        const float* __restrict__ xf_in, const _Float16* __restrict__ part,
        const float* __restrict__ bias, const float* __restrict__ g,
        const float* __restrict__ bb, float* __restrict__ xo,
        _Float16* __restrict__ xh) {
    const int row = blockIdx.x, t = threadIdx.x;
    const int d0 = t * 4;
    const size_t base = (size_t)row * D_MODEL + d0;

    const float4 xv = *(const float4*)&xf_in[base];
    const float4 bv = *(const float4*)&bias[d0];
    float s[4] = {xv.x + bv.x, xv.y + bv.y, xv.z + bv.z, xv.w + bv.w};
#pragma unroll
    for (int p = 0; p < SPLIT; ++p) {
        const half4v pv = *(const half4v*)&part[(size_t)p * MTOT * D_MODEL + base];
#pragma unroll
        for (int i = 0; i < 4; ++i) s[i] += (float)pv[i];
    }
    float sum = s[0] + s[1] + s[2] + s[3];
    float sq = s[0]*s[0] + s[1]*s[1] + s[2]*s[2] + s[3]*s[3];
#pragma unroll
    for (int off = 1; off < 64; off <<= 1) {
        sum += __shfl_xor(sum, off, 64);
        sq  += __shfl_xor(sq, off, 64);
    }
    __shared__ float red[8];
    if ((t & 63) == 0) { red[(t >> 6) * 2] = sum; red[(t >> 6) * 2 + 1] = sq; }
    __syncthreads();
    sum = red[0] + red[2] + red[4] + red[6];
    sq  = red[1] + red[3] + red[5] + red[7];
    const float mean = sum * (1.0f / 1024.0f);
    const float var = sq * (1.0f / 1024.0f) - mean * mean;
    const float rstd = rsqrtf(var + 1e-5f);

    const float4 gv = *(const float4*)&g[d0];
    const float4 bbv = *(const float4*)&bb[d0];
    float o[4];
    o[0] = (s[0] - mean) * rstd * gv.x + bbv.x;
    o[1] = (s[1] - mean) * rstd * gv.y + bbv.y;
    o[2] = (s[2] - mean) * rstd * gv.z + bbv.z;
    o[3] = (s[3] - mean) * rstd * gv.w + bbv.w;
    *(float4*)&xo[base] = (float4){o[0], o[1], o[2], o[3]};
    half4v oh;
#pragma unroll
    for (int i = 0; i < 4; ++i) oh[i] = (_Float16)o[i];
    *(half4v*)&xh[base] = oh;
}

// ---------------------------------------------------------------------- host
extern "C" void kernel_launch(void* const* d_in, const int* in_sizes, int n_in,
                              void* d_out, int out_size, void* d_ws, size_t ws_size,
                              hipStream_t stream) {
    const float* x    = (const float*)d_in[0];
    const float* mask = (const float*)d_in[1];
    const float* Wq = (const float*)d_in[2];  const float* bq = (const float*)d_in[3];
    const float* Wk = (const float*)d_in[4];  const float* bk = (const float*)d_in[5];
    const float* Wv = (const float*)d_in[6];  const float* bv = (const float*)d_in[7];
    const float* Wo = (const float*)d_in[8];  const float* bo = (const float*)d_in[9];
    const float* W1 = (const float*)d_in[10]; const float* b1 = (const float*)d_in[11];
    const float* W2 = (const float*)d_in[12]; const float* b2 = (const float*)d_in[13];
    const float* lng = (const float*)d_in[14]; const float* lnb = (const float*)d_in[15];
    float* xf = (float*)d_out;

    char* w = (char*)d_ws;
    const size_t MB = 1048576;
    _Float16* xh    = (_Float16*)(w);                 // [0,8M)
    _Float16* qkv   = (_Float16*)(w + 8 * MB);        // [8M,32M)  q,k
    _Float16* oh    = (_Float16*)(w + 32 * MB);       // [32M,40M) attn out
    _Float16* part  = (_Float16*)(w + 40 * MB);       // [40M,72M) split-K partials (4x)
    _Float16* vT    = (_Float16*)(w + 40 * MB);       // aliases part (disjoint in time)
    _Float16* hh    = (_Float16*)(w + 72 * MB);       // [72M,104M) ffn hidden
    _Float16* wqkvT = (_Float16*)(w + 104 * MB);      // [104M,110M)
    _Float16* woT   = (_Float16*)(w + 110 * MB);      // [110M,112M)
    _Float16* w1T   = (_Float16*)(w + 8 * MB);        // aliases q (dead after attn)
    _Float16* w2T   = (_Float16*)(w + 16 * MB);       // aliases k (dead after attn)

    posenc_kernel<<<MTOT, 256, 0, stream>>>(x, xf, xh);

    for (int l = 0; l < NLAYER; ++l) {
        transpose_qkv_kernel<<<dim3(32, 32, 3), 256, 0, stream>>>(Wq, Wk, Wv, l, wqkvT);
        transpose_cvt_kernel<<<dim3(32, 32, 1), 256, 0, stream>>>(
            Wo + (size_t)l * 1048576, woT, 1024, 1024);

        gemm256_kernel<0, 1><<<dim3(12, 16), 512, 0, stream>>>(
            xh, wqkvT, bq + l * 1024, bk + l * 1024, bv + l * 1024,
            qkv, vT, MTOT, 3072, 1024);
        attn_kernel<<<dim3(16, 64), 256, 0, stream>>>(
            qkv, qkv + (size_t)MTOT * D_MODEL, vT, oh, mask);

        // q,k now dead -> stage W1^T/W2^T into their space
        transpose_cvt_kernel<<<dim3(128, 32, 1), 256, 0, stream>>>(
            W1 + (size_t)l * 4194304, w1T, 1024, 4096);
        transpose_cvt_kernel<<<dim3(32, 128, 1), 256, 0, stream>>>(
            W2 + (size_t)l * 4194304, w2T, 4096, 1024);

        gemm256_kernel<3, 4><<<dim3(4, 16, 4), 512, 0, stream>>>(
            oh, woT, nullptr, nullptr, nullptr, part, nullptr, MTOT, 1024, 1024);
        ln_fused_kernel<4><<<MTOT, 256, 0, stream>>>(
            xf, part, bo + l * 1024,
            lng + (size_t)(2 * l) * 1024, lnb + (size_t)(2 * l) * 1024, xf, xh);

        gemm256_kernel<2, 1><<<dim3(16, 16), 512, 0, stream>>>(
            xh, w1T, b1 + l * 4096, nullptr, nullptr, hh, nullptr, MTOT, 4096, 1024);
        gemm256_kernel<3, 4><<<dim3(4, 16, 4), 512, 0, stream>>>(
            hh, w2T, nullptr, nullptr, nullptr, part, nullptr, MTOT, 1024, 4096);
        ln_fused_kernel<4><<<MTOT, 256, 0, stream>>>(
            xf, part, b2 + l * 1024,
            lng + (size_t)(2 * l + 1) * 1024, lnb + (size_t)(2 * l + 1) * 1024,
            xf, xh);
    }
}

// Round 2
// 1618.095 us; speedup vs baseline: 1.2962x; 1.0337x over previous
//
#include <hip/hip_runtime.h>

#define D_MODEL 1024
#define NH      16
#define DHEAD   64
#define DFF     4096
#define BATCH   4
#define SEQ     1024
#define NLAYER  6
#define MTOT    (BATCH*SEQ)   // 4096 rows

typedef _Float16 half8 __attribute__((ext_vector_type(8)));
typedef _Float16 half4v __attribute__((ext_vector_type(4)));
typedef float   floatx4 __attribute__((ext_vector_type(4)));

static __device__ __forceinline__ floatx4 mfma16(half8 a, half8 b, floatx4 c) {
    return __builtin_amdgcn_mfma_f32_16x16x32_f16(a, b, c, 0, 0, 0);
}

// async global->LDS, 16B per lane; global src addr is PER-LANE, lds dst is
// wave-uniform base + lane*16B (linear).
static __device__ __forceinline__ void gl_lds16(const _Float16* g, _Float16* l) {
    __builtin_amdgcn_global_load_lds(
        (const __attribute__((address_space(1))) _Float16*)g,
        (__attribute__((address_space(3))) _Float16*)l, 16, 0, 0);
}

// counted vmem wait (NEVER vmcnt(0) in the GEMM main loop)
#define VMCNT(n) asm volatile("s_waitcnt vmcnt(" #n ")" ::: "memory")

// ---------------------------------------------------------------- pos encode
__global__ __launch_bounds__(256) void posenc_kernel(
        const float* __restrict__ xin, float* __restrict__ xf,
        _Float16* __restrict__ xh) {
    const int row = blockIdx.x;            // b*S + s
    const int s = row & (SEQ - 1);
    const float neg_log_inc = -9.210340371976184f / 511.0f;  // -ln(1e4)/(nt-1)
#pragma unroll
    for (int i = 0; i < 4; ++i) {
        const int d = threadIdx.x + i * 256;
        const int j = d & 511;
        const float inv = expf((float)j * neg_log_inc);
        const float arg = (float)s * inv;
        const float sig = (d < 512) ? sinf(arg) : cosf(arg);
        const float v = xin[(size_t)row * D_MODEL + d] + sig;
        xf[(size_t)row * D_MODEL + d] = v;
        xh[(size_t)row * D_MODEL + d] = (_Float16)v;
    }
}

// ------------------------------------------------- weight transpose + cvt f16
__global__ __launch_bounds__(256) void transpose_cvt_kernel(
        const float* __restrict__ src, _Float16* __restrict__ dst, int R, int C) {
    __shared__ float tile[32][33];
    const size_t zoff = (size_t)blockIdx.z * R * C;
    src += zoff; dst += zoff;
    const int cb = blockIdx.x * 32, rb = blockIdx.y * 32;
    const int tx = threadIdx.x & 31, ty = threadIdx.x >> 5;
#pragma unroll
    for (int i = 0; i < 4; ++i)
        tile[ty + i * 8][tx] = src[(size_t)(rb + ty + i * 8) * C + cb + tx];
    __syncthreads();
#pragma unroll
    for (int i = 0; i < 4; ++i)
        dst[(size_t)(cb + ty + i * 8) * R + rb + tx] = (_Float16)tile[tx][ty + i * 8];
}

__global__ __launch_bounds__(256) void transpose_qkv_kernel(
        const float* __restrict__ Wq, const float* __restrict__ Wk,
        const float* __restrict__ Wv, int layer, _Float16* __restrict__ dst) {
    __shared__ float tile[32][33];
    const int z = blockIdx.z;
    const float* src = (z == 0 ? Wq : (z == 1 ? Wk : Wv))
                       + (size_t)layer * D_MODEL * D_MODEL;
    _Float16* dz = dst + (size_t)z * D_MODEL * D_MODEL;
    const int cb = blockIdx.x * 32, rb = blockIdx.y * 32;
    const int tx = threadIdx.x & 31, ty = threadIdx.x >> 5;
#pragma unroll
    for (int i = 0; i < 4; ++i)
        tile[ty + i * 8][tx] = src[(size_t)(rb + ty + i * 8) * D_MODEL + cb + tx];
    __syncthreads();
#pragma unroll
    for (int i = 0; i < 4; ++i)
        dz[(size_t)(cb + ty + i * 8) * D_MODEL + rb + tx] = (_Float16)tile[tx][ty + i * 8];
}

// ---------------------------------------------------------------- NT GEMM 256²
// 256x256 tile, 8 waves (2M x 4N), BK=32, 4 LDS buffers (128 KiB), depth-3
// prefetch with counted vmcnt, raw s_barrier (1 per K-tile), setprio around
// the MFMA cluster.
//
// COALESCED staging (round-2 fix): per load unit, lane=(row=lane>>2,
// kchunk=lane&3) so 4 consecutive lanes fetch one row's full 64B K-slice —
// exactly one cache line, fully used (was: 64-line stride-2KB gather, 4x L2
// transaction cost, the round-1 stall). LDS layout is therefore row-major
// [buf][256][32] (row stride 64B); fragment read = &s[buf][row][quad*8].
//
// Pipeline invariants (per wave, 4 loads per issue()):
//   issue(t+3) overwrites buf((t-1)&3) — all waves finished reading t-1
//   before the barrier that precedes this issue;
//   end of tile t: vmcnt(8) leaves exactly tiles t+2,t+3 in flight -> t+1
//   landed; barrier publishes it to all waves.
//
// MODE 0: qkv fused; q,k -> outp (scaled q), v -> outp2 as vT[b][h][dh][s]
// MODE 2: relu(+bias0), f16 out [M][N]
// MODE 3: split-K raw f16 partial out at outp + z*M*N (bias added in LN)
template<int MODE, int SPLIT>
__global__ __launch_bounds__(512, 2) void gemm256_kernel(
        const _Float16* __restrict__ A, const _Float16* __restrict__ BT,
        const float* __restrict__ bias0, const float* __restrict__ bias1,
        const float* __restrict__ bias2, void* __restrict__ outp,
        void* __restrict__ outp2, int M, int N, int K) {
    __shared__ alignas(16) _Float16 a_s[4][256][32];   // [buf][row][k]
    __shared__ alignas(16) _Float16 b_s[4][256][32];

    // ---- XCD-locality swizzle (requires (gridDim.y*gridDim.z)%8==0)
    const int l = blockIdx.x + gridDim.x * (blockIdx.y + gridDim.y * blockIdx.z);
    const int xcd = l & 7, j = l >> 3;
    const int bx = j % gridDim.x;
    const int g = xcd + 8 * (j / gridDim.x);
    const int bz = g % gridDim.z;
    const int by = g / gridDim.z;

    const int t = threadIdx.x;
    const int wv = t >> 6, lane = t & 63, quad = lane >> 4, lm = lane & 15;
    const int wm = wv >> 2, wn = wv & 3;       // wave tile: rows wm*128, cols wn*64
    const int mb = by * 256, nb = bx * 256;

    const int Keff = K / SPLIT;
    const int k0 = (SPLIT > 1) ? bz * Keff : 0;

    // staging role: waves 0-3 stage A row-groups 0-3, waves 4-7 stage B
    const int sop = wv >> 2, wgrp = wv & 3;
    const int lrow = lane >> 2, lcol = lane & 3;   // 16 rows x 4 chunks per load
    const _Float16* gbase = (sop ? (BT + (size_t)(nb + wgrp * 64 + lrow) * K)
                                 : (A + (size_t)(mb + wgrp * 64 + lrow) * K))
                            + k0 + lcol * 8;
    _Float16* sb0 = sop ? &b_s[0][wgrp * 64][0] : &a_s[0][wgrp * 64][0];

    auto issue = [&](int tt) {
        const _Float16* gp = gbase + tt * 32;
        _Float16* dp = sb0 + (size_t)(tt & 3) * 8192;   // buf stride 256*32 halves
#pragma unroll
        for (int u = 0; u < 4; ++u)                     // 16 rows per load
            gl_lds16(gp + (size_t)(u * 16) * K, dp + u * 512);
    };

    floatx4 acc[8][4];
#pragma unroll
    for (int i = 0; i < 8; ++i)
#pragma unroll
        for (int jj = 0; jj < 4; ++jj) acc[i][jj] = (floatx4){0.f, 0.f, 0.f, 0.f};

    auto compute = [&](int buf) {
        half8 bfr[4];
#pragma unroll
        for (int nf = 0; nf < 4; ++nf)
            bfr[nf] = *(const half8*)&b_s[buf][wn * 64 + nf * 16 + lm][quad * 8];
        __builtin_amdgcn_s_setprio(1);
#pragma unroll
        for (int mf = 0; mf < 8; ++mf) {
            const half8 am = *(const half8*)&a_s[buf][wm * 128 + mf * 16 + lm][quad * 8];
#pragma unroll
            for (int nf = 0; nf < 4; ++nf)
                acc[mf][nf] = mfma16(am, bfr[nf], acc[mf][nf]);
        }
        __builtin_amdgcn_s_setprio(0);
    };

    const int NT = Keff >> 5;                 // >= 8 in all launches
    issue(0); issue(1); issue(2);
    VMCNT(8);                                 // tile 0 landed; 1,2 in flight
    __builtin_amdgcn_s_barrier();
    __builtin_amdgcn_sched_barrier(0);

    for (int tt = 0; tt < NT - 3; ++tt) {
        issue(tt + 3);                        // buf((tt-1)&3): retired last iter
        compute(tt & 3);
        VMCNT(8);                             // t+1 landed; t+2,t+3 in flight
        __builtin_amdgcn_s_barrier();
        __builtin_amdgcn_sched_barrier(0);
    }
    compute((NT - 3) & 3);
    VMCNT(4);                                 // NT-2 landed; NT-1 in flight
    __builtin_amdgcn_s_barrier();
    __builtin_amdgcn_sched_barrier(0);
    compute((NT - 2) & 3);
    VMCNT(0);                                 // NT-1 landed (tail only)
    __builtin_amdgcn_s_barrier();
    __builtin_amdgcn_sched_barrier(0);
    compute((NT - 1) & 3);

    // ------------------------------------------------------------- epilogue
#pragma unroll
    for (int mf = 0; mf < 8; ++mf) {
#pragma unroll
        for (int nf = 0; nf < 4; ++nf) {
            const int row0 = mb + wm * 128 + mf * 16 + quad * 4;
            const int col = nb + wn * 64 + nf * 16 + lm;
            if (MODE == 0 && (col >> 10) == 2) {
                // v -> vT[b][h][dh][s]; 4 r-values are 4 consecutive s
                const int nn = col & 1023, h = nn >> 6, dh = nn & 63;
                const int b = row0 >> 10, s0 = row0 & 1023;
                const float bias = bias2[nn];
                half4v v4;
#pragma unroll
                for (int r = 0; r < 4; ++r) v4[r] = (_Float16)(acc[mf][nf][r] + bias);
                *(half4v*)&((_Float16*)outp2)[
                    (size_t)((b * NH + h) * DHEAD + dh) * SEQ + s0] = v4;
                continue;
            }
#pragma unroll
            for (int r = 0; r < 4; ++r) {
                float v = acc[mf][nf][r];
                const int row = row0 + r;
                if (MODE == 0) {
                    const int sel = col >> 10, nn = col & 1023;
                    v += (sel == 0 ? bias0 : bias1)[nn];
                    if (sel == 0) v *= 0.125f;     // DH^-0.5
                    ((_Float16*)outp)[(size_t)sel * MTOT * D_MODEL +
                                      (size_t)row * D_MODEL + nn] = (_Float16)v;
                } else if (MODE == 2) {
                    v = fmaxf(v + bias0[col], 0.f);
                    ((_Float16*)outp)[(size_t)row * N + col] = (_Float16)v;
                } else {   // MODE 3: raw f16 partial
                    ((_Float16*)outp)[(size_t)bz * M * N +
                                      (size_t)row * N + col] = (_Float16)v;
                }
            }
        }
    }
}

// ------------------------------------------------------------ flash attention
// block = (b,h) x 64 q-rows; wave w owns q-rows q0+w*16..+15, all keys.
__global__ __launch_bounds__(256) void attn_kernel(
        const _Float16* __restrict__ q, const _Float16* __restrict__ k,
        const _Float16* __restrict__ vT, _Float16* __restrict__ o,
        const float* __restrict__ mask) {
    const int b = blockIdx.y >> 4, h = blockIdx.y & 15;
    const int q0 = blockIdx.x * 64;
    const int t = threadIdx.x;
    const int wv = t >> 6, lane = t & 63, quad = lane >> 4, lm = lane & 15;

    __shared__ alignas(16) _Float16 k_s[512 * 8];
    __shared__ alignas(16) _Float16 v_s[512 * 8];
    __shared__ alignas(16) _Float16 p_s[4][16][72];

    const _Float16* kb = k + (size_t)b * SEQ * D_MODEL + h * 64;
    const _Float16* vb = vT + (size_t)(b * NH + h) * DHEAD * SEQ;
    int koff[2], voff[2];
#pragma unroll
    for (int jj = 0; jj < 2; ++jj) {
        const int c = t + jj * 256;
        const int row = c >> 3, gg = (c & 7) ^ (row & 7);
        koff[jj] = row * D_MODEL + gg * 8;
        voff[jj] = row * SEQ + gg * 8;
    }
    _Float16* kdst0 = k_s + (size_t)(wv * 64) * 8;
    _Float16* kdst1 = kdst0 + 256 * 8;
    _Float16* vdst0 = v_s + (size_t)(wv * 64) * 8;
    _Float16* vdst1 = vdst0 + 256 * 8;

    half8 qf[2];
    {
        const size_t qrow = (size_t)(b * SEQ + q0 + wv * 16 + lm);
#pragma unroll
        for (int ks = 0; ks < 2; ++ks)
            qf[ks] = *(const half8*)(q + qrow * D_MODEL + h * 64 + ks * 32 + quad * 8);
    }

    float l_part[4] = {0.f, 0.f, 0.f, 0.f};
    floatx4 Oacc[4];
#pragma unroll
    for (int nt = 0; nt < 4; ++nt) Oacc[nt] = (floatx4){0.f, 0.f, 0.f, 0.f};

    for (int jb = 0; jb < 16; ++jb) {
        const int kk0 = jb * 64;
        __syncthreads();
        gl_lds16(kb + kk0 * D_MODEL + koff[0], kdst0);
        gl_lds16(kb + kk0 * D_MODEL + koff[1], kdst1);
        gl_lds16(vb + kk0 + voff[0], vdst0);
        gl_lds16(vb + kk0 + voff[1], vdst1);
        __syncthreads();

        floatx4 sacc[4];
#pragma unroll
        for (int nt = 0; nt < 4; ++nt) {
            sacc[nt] = (floatx4){0.f, 0.f, 0.f, 0.f};
            const int row = nt * 16 + lm;
#pragma unroll
            for (int ks = 0; ks < 2; ++ks) {
                const int gg = (ks * 4 + quad) ^ (lm & 7);
                const half8 kf = *(const half8*)&k_s[row * 64 + gg * 8];
                sacc[nt] = mfma16(qf[ks], kf, sacc[nt]);
            }
        }
#pragma unroll
        for (int nt = 0; nt < 4; ++nt) {
            const float madd = (1.0f - mask[b * SEQ + kk0 + nt * 16 + lm]) * (-1.0e8f);
#pragma unroll
            for (int r = 0; r < 4; ++r) {
                const float p = __expf(sacc[nt][r] + madd);
                l_part[r] += p;
                p_s[wv][quad * 4 + r][nt * 16 + lm] = (_Float16)p;
            }
        }
#pragma unroll
        for (int ks = 0; ks < 2; ++ks) {
            const half8 pf = *(const half8*)&p_s[wv][lm][ks * 32 + quad * 8];
#pragma unroll
            for (int nt = 0; nt < 4; ++nt) {
                const int row = nt * 16 + lm;
                const int gg = (ks * 4 + quad) ^ (lm & 7);
                const half8 vf = *(const half8*)&v_s[row * 64 + gg * 8];
                Oacc[nt] = mfma16(pf, vf, Oacc[nt]);
            }
        }
    }
#pragma unroll
    for (int r = 0; r < 4; ++r) {
        float v = l_part[r];
#pragma unroll
        for (int off = 1; off < 16; off <<= 1) v += __shfl_xor(v, off, 64);
        l_part[r] = 1.0f / v;
    }
#pragma unroll
    for (int nt = 0; nt < 4; ++nt)
#pragma unroll
        for (int r = 0; r < 4; ++r) {
            const float v = Oacc[nt][r] * l_part[r];
            o[(size_t)(b * SEQ + q0 + wv * 16 + quad * 4 + r) * D_MODEL +
              h * 64 + nt * 16 + lm] = (_Float16)v;
        }
}

// --------------------------------------- residual + split-K reduce + bias + LN
template<int SPLIT>
__global__ __launch_bounds__(256) void ln_fused_kernel(
        const float* __restrict__ xf_in, const _Float16* __restrict__ part,
        const float* __restrict__ bias, const float* __restrict__ g,
        const float* __restrict__ bb, float* __restrict__ xo,
        _Float16* __restrict__ xh) {
    const int row = blockIdx.x, t = threadIdx.x;
    const int d0 = t * 4;
    const size_t base = (size_t)row * D_MODEL + d0;

    const float4 xv = *(const float4*)&xf_in[base];
    const float4 bv = *(const float4*)&bias[d0];
    float s[4] = {xv.x + bv.x, xv.y + bv.y, xv.z + bv.z, xv.w + bv.w};
#pragma unroll
    for (int p = 0; p < SPLIT; ++p) {
        const half4v pv = *(const half4v*)&part[(size_t)p * MTOT * D_MODEL + base];
#pragma unroll
        for (int i = 0; i < 4; ++i) s[i] += (float)pv[i];
    }
    float sum = s[0] + s[1] + s[2] + s[3];
    float sq = s[0]*s[0] + s[1]*s[1] + s[2]*s[2] + s[3]*s[3];
#pragma unroll
    for (int off = 1; off < 64; off <<= 1) {
        sum += __shfl_xor(sum, off, 64);
        sq  += __shfl_xor(sq, off, 64);
    }
    __shared__ float red[8];
    if ((t & 63) == 0) { red[(t >> 6) * 2] = sum; red[(t >> 6) * 2 + 1] = sq; }
    __syncthreads();
    sum = red[0] + red[2] + red[4] + red[6];
    sq  = red[1] + red[3] + red[5] + red[7];
    const float mean = sum * (1.0f / 1024.0f);
    const float var = sq * (1.0f / 1024.0f) - mean * mean;
    const float rstd = rsqrtf(var + 1e-5f);

    const float4 gv = *(const float4*)&g[d0];
    const float4 bbv = *(const float4*)&bb[d0];
    float o[4];
    o[0] = (s[0] - mean) * rstd * gv.x + bbv.x;
    o[1] = (s[1] - mean) * rstd * gv.y + bbv.y;
    o[2] = (s[2] - mean) * rstd * gv.z + bbv.z;
    o[3] = (s[3] - mean) * rstd * gv.w + bbv.w;
    *(float4*)&xo[base] = (float4){o[0], o[1], o[2], o[3]};
    half4v oh;
#pragma unroll
    for (int i = 0; i < 4; ++i) oh[i] = (_Float16)o[i];
    *(half4v*)&xh[base] = oh;
}

// ---------------------------------------------------------------------- host
extern "C" void kernel_launch(void* const* d_in, const int* in_sizes, int n_in,
                              void* d_out, int out_size, void* d_ws, size_t ws_size,
                              hipStream_t stream) {
    const float* x    = (const float*)d_in[0];
    const float* mask = (const float*)d_in[1];
    const float* Wq = (const float*)d_in[2];  const float* bq = (const float*)d_in[3];
    const float* Wk = (const float*)d_in[4];  const float* bk = (const float*)d_in[5];
    const float* Wv = (const float*)d_in[6];  const float* bv = (const float*)d_in[7];
    const float* Wo = (const float*)d_in[8];  const float* bo = (const float*)d_in[9];
    const float* W1 = (const float*)d_in[10]; const float* b1 = (const float*)d_in[11];
    const float* W2 = (const float*)d_in[12]; const float* b2 = (const float*)d_in[13];
    const float* lng = (const float*)d_in[14]; const float* lnb = (const float*)d_in[15];
    float* xf = (float*)d_out;

    char* w = (char*)d_ws;
    const size_t MB = 1048576;
    _Float16* xh    = (_Float16*)(w);                 // [0,8M)
    _Float16* qkv   = (_Float16*)(w + 8 * MB);        // [8M,32M)  q,k
    _Float16* oh    = (_Float16*)(w + 32 * MB);       // [32M,40M) attn out
    _Float16* part  = (_Float16*)(w + 40 * MB);       // [40M,72M) split-K partials (4x)
    _Float16* vT    = (_Float16*)(w + 40 * MB);       // aliases part (disjoint in time)
    _Float16* hh    = (_Float16*)(w + 72 * MB);       // [72M,104M) ffn hidden
    _Float16* wqkvT = (_Float16*)(w + 104 * MB);      // [104M,110M)
    _Float16* woT   = (_Float16*)(w + 110 * MB);      // [110M,112M)
    _Float16* w1T   = (_Float16*)(w + 8 * MB);        // aliases q (dead after attn)
    _Float16* w2T   = (_Float16*)(w + 16 * MB);       // aliases k (dead after attn)

    posenc_kernel<<<MTOT, 256, 0, stream>>>(x, xf, xh);

    for (int l = 0; l < NLAYER; ++l) {
        transpose_qkv_kernel<<<dim3(32, 32, 3), 256, 0, stream>>>(Wq, Wk, Wv, l, wqkvT);
        transpose_cvt_kernel<<<dim3(32, 32, 1), 256, 0, stream>>>(
            Wo + (size_t)l * 1048576, woT, 1024, 1024);

        gemm256_kernel<0, 1><<<dim3(12, 16), 512, 0, stream>>>(
            xh, wqkvT, bq + l * 1024, bk + l * 1024, bv + l * 1024,
            qkv, vT, MTOT, 3072, 1024);
        attn_kernel<<<dim3(16, 64), 256, 0, stream>>>(
            qkv, qkv + (size_t)MTOT * D_MODEL, vT, oh, mask);

        // q,k now dead -> stage W1^T/W2^T into their space
        transpose_cvt_kernel<<<dim3(128, 32, 1), 256, 0, stream>>>(
            W1 + (size_t)l * 4194304, w1T, 1024, 4096);
        transpose_cvt_kernel<<<dim3(32, 128, 1), 256, 0, stream>>>(
            W2 + (size_t)l * 4194304, w2T, 4096, 1024);

        gemm256_kernel<3, 4><<<dim3(4, 16, 4), 512, 0, stream>>>(
            oh, woT, nullptr, nullptr, nullptr, part, nullptr, MTOT, 1024, 1024);
        ln_fused_kernel<4><<<MTOT, 256, 0, stream>>>(
            xf, part, bo + l * 1024,
            lng + (size_t)(2 * l) * 1024, lnb + (size_t)(2 * l) * 1024, xf, xh);

        gemm256_kernel<2, 1><<<dim3(16, 16), 512, 0, stream>>>(
            xh, w1T, b1 + l * 4096, nullptr, nullptr, hh, nullptr, MTOT, 4096, 1024);
        gemm256_kernel<3, 4><<<dim3(4, 16, 4), 512, 0, stream>>>(
            hh, w2T, nullptr, nullptr, nullptr, part, nullptr, MTOT, 1024, 4096);
        ln_fused_kernel<4><<<MTOT, 256, 0, stream>>>(
            xf, part, b2 + l * 1024,
            lng + (size_t)(2 * l + 1) * 1024, lnb + (size_t)(2 * l + 1) * 1024,
            xf, xh);
    }
}

// Round 3
// 1611.448 us; speedup vs baseline: 1.3016x; 1.0041x over previous
//
#include <hip/hip_runtime.h>

#define D_MODEL 1024
#define NH      16
#define DHEAD   64
#define DFF     4096
#define BATCH   4
#define SEQ     1024
#define NLAYER  6
#define MTOT    (BATCH*SEQ)   // 4096 rows

typedef _Float16 half8 __attribute__((ext_vector_type(8)));
typedef _Float16 half4v __attribute__((ext_vector_type(4)));
typedef float   floatx4 __attribute__((ext_vector_type(4)));

static __device__ __forceinline__ floatx4 mfma16(half8 a, half8 b, floatx4 c) {
    return __builtin_amdgcn_mfma_f32_16x16x32_f16(a, b, c, 0, 0, 0);
}

// async global->LDS, 16B per lane; global src addr is PER-LANE, lds dst is
// wave-uniform base + lane*16B (linear).
static __device__ __forceinline__ void gl_lds16(const _Float16* g, _Float16* l) {
    __builtin_amdgcn_global_load_lds(
        (const __attribute__((address_space(1))) _Float16*)g,
        (__attribute__((address_space(3))) _Float16*)l, 16, 0, 0);
}

// counted vmem wait (NEVER vmcnt(0) in the GEMM main loop)
#define VMCNT(n) asm volatile("s_waitcnt vmcnt(" #n ")" ::: "memory")

// ---------------------------------------------------------------- pos encode
__global__ __launch_bounds__(256) void posenc_kernel(
        const float* __restrict__ xin, float* __restrict__ xf,
        _Float16* __restrict__ xh) {
    const int row = blockIdx.x;            // b*S + s
    const int s = row & (SEQ - 1);
    const float neg_log_inc = -9.210340371976184f / 511.0f;  // -ln(1e4)/(nt-1)
#pragma unroll
    for (int i = 0; i < 4; ++i) {
        const int d = threadIdx.x + i * 256;
        const int j = d & 511;
        const float inv = expf((float)j * neg_log_inc);
        const float arg = (float)s * inv;
        const float sig = (d < 512) ? sinf(arg) : cosf(arg);
        const float v = xin[(size_t)row * D_MODEL + d] + sig;
        xf[(size_t)row * D_MODEL + d] = v;
        xh[(size_t)row * D_MODEL + d] = (_Float16)v;
    }
}

// ------------------------------------------------- weight transpose + cvt f16
__global__ __launch_bounds__(256) void transpose_cvt_kernel(
        const float* __restrict__ src, _Float16* __restrict__ dst, int R, int C) {
    __shared__ float tile[32][33];
    const size_t zoff = (size_t)blockIdx.z * R * C;
    src += zoff; dst += zoff;
    const int cb = blockIdx.x * 32, rb = blockIdx.y * 32;
    const int tx = threadIdx.x & 31, ty = threadIdx.x >> 5;
#pragma unroll
    for (int i = 0; i < 4; ++i)
        tile[ty + i * 8][tx] = src[(size_t)(rb + ty + i * 8) * C + cb + tx];
    __syncthreads();
#pragma unroll
    for (int i = 0; i < 4; ++i)
        dst[(size_t)(cb + ty + i * 8) * R + rb + tx] = (_Float16)tile[tx][ty + i * 8];
}

__global__ __launch_bounds__(256) void transpose_qkv_kernel(
        const float* __restrict__ Wq, const float* __restrict__ Wk,
        const float* __restrict__ Wv, int layer, _Float16* __restrict__ dst) {
    __shared__ float tile[32][33];
    const int z = blockIdx.z;
    const float* src = (z == 0 ? Wq : (z == 1 ? Wk : Wv))
                       + (size_t)layer * D_MODEL * D_MODEL;
    _Float16* dz = dst + (size_t)z * D_MODEL * D_MODEL;
    const int cb = blockIdx.x * 32, rb = blockIdx.y * 32;
    const int tx = threadIdx.x & 31, ty = threadIdx.x >> 5;
#pragma unroll
    for (int i = 0; i < 4; ++i)
        tile[ty + i * 8][tx] = src[(size_t)(rb + ty + i * 8) * D_MODEL + cb + tx];
    __syncthreads();
#pragma unroll
    for (int i = 0; i < 4; ++i)
        dz[(size_t)(cb + ty + i * 8) * D_MODEL + rb + tx] = (_Float16)tile[tx][ty + i * 8];
}

// ---------------------------------------------------------------- NT GEMM 256²
// 256x256 tile, 8 waves (2M x 4N), BK=32, 4 LDS buffers (128 KiB), depth-3
// prefetch with counted vmcnt, raw s_barrier (1 per K-tile), setprio around
// the MFMA cluster.
//
// Staging (round-3): coalesced global source + XOR-swizzled LDS layout,
// swizzle applied on BOTH sides (source pre-swizzle + read swizzle), LDS
// dest linear (rule: global_load_lds writes base+lane*16B only).
//   physical layout: chunk c of row r at slot (c ^ ((r>>1)&3)), row stride
//   64B. Lane l of a load unit: row=l>>2, slot=l&3, fetches global chunk
//   (l&3)^((l>>3)&3) -> every 4-lane group covers one full 64B line
//   (coalesced); read of k-chunk `quad` at row (..+lm) uses slot
//   quad^((lm>>1)&3) -> bank granule 4*(lm&1)+(quad^((lm>>1)&3)) covers all
//   8 granules exactly 2x per 16-lane group = 2-way = free (m136).
//
// Pipeline invariants (per wave, 4 loads per issue()):
//   issue(t+3) overwrites buf((t-1)&3) — all waves finished reading t-1
//   before the barrier that precedes this issue;
//   end of tile t: vmcnt(8) leaves exactly tiles t+2,t+3 in flight -> t+1
//   landed; barrier publishes it to all waves.
//
// MODE 0: qkv fused; q,k -> outp (scaled q), v -> outp2 as vT[b][h][dh][s]
// MODE 2: relu(+bias0), f16 out [M][N]
// MODE 3: split-K raw f16 partial out at outp + z*M*N (bias added in LN)
template<int MODE, int SPLIT>
__global__ __launch_bounds__(512, 2) void gemm256_kernel(
        const _Float16* __restrict__ A, const _Float16* __restrict__ BT,
        const float* __restrict__ bias0, const float* __restrict__ bias1,
        const float* __restrict__ bias2, void* __restrict__ outp,
        void* __restrict__ outp2, int M, int N, int K) {
    __shared__ alignas(16) _Float16 a_s[4][256][32];   // [buf][row][swizzled k]
    __shared__ alignas(16) _Float16 b_s[4][256][32];

    // ---- XCD-locality swizzle (requires (gridDim.y*gridDim.z)%8==0)
    const int l = blockIdx.x + gridDim.x * (blockIdx.y + gridDim.y * blockIdx.z);
    const int xcd = l & 7, j = l >> 3;
    const int bx = j % gridDim.x;
    const int g = xcd + 8 * (j / gridDim.x);
    const int bz = g % gridDim.z;
    const int by = g / gridDim.z;

    const int t = threadIdx.x;
    const int wv = t >> 6, lane = t & 63, quad = lane >> 4, lm = lane & 15;
    const int wm = wv >> 2, wn = wv & 3;       // wave tile: rows wm*128, cols wn*64
    const int mb = by * 256, nb = bx * 256;

    const int Keff = K / SPLIT;
    const int k0 = (SPLIT > 1) ? bz * Keff : 0;

    // staging role: waves 0-3 stage A row-groups 0-3, waves 4-7 stage B
    const int sop = wv >> 2, wgrp = wv & 3;
    const int lrow = lane >> 2;                          // 16 rows x 4 chunks
    const int gchunk = (lane & 3) ^ ((lane >> 3) & 3);   // source pre-swizzle
    const _Float16* gbase = (sop ? (BT + (size_t)(nb + wgrp * 64 + lrow) * K)
                                 : (A + (size_t)(mb + wgrp * 64 + lrow) * K))
                            + k0 + gchunk * 8;
    _Float16* sb0 = sop ? &b_s[0][wgrp * 64][0] : &a_s[0][wgrp * 64][0];

    auto issue = [&](int tt) {
        const _Float16* gp = gbase + tt * 32;
        _Float16* dp = sb0 + (size_t)(tt & 3) * 8192;   // buf stride 256*32 halves
#pragma unroll
        for (int u = 0; u < 4; ++u)                     // 16 rows per load
            gl_lds16(gp + (size_t)(u * 16) * K, dp + u * 512);
    };

    floatx4 acc[8][4];
#pragma unroll
    for (int i = 0; i < 8; ++i)
#pragma unroll
        for (int jj = 0; jj < 4; ++jj) acc[i][jj] = (floatx4){0.f, 0.f, 0.f, 0.f};

    const int rsw = (quad ^ ((lm >> 1) & 3)) * 8;       // read-side swizzle

    auto compute = [&](int buf) {
        half8 bfr[4];
#pragma unroll
        for (int nf = 0; nf < 4; ++nf)
            bfr[nf] = *(const half8*)&b_s[buf][wn * 64 + nf * 16 + lm][rsw];
        __builtin_amdgcn_s_setprio(1);
#pragma unroll
        for (int mf = 0; mf < 8; ++mf) {
            const half8 am = *(const half8*)&a_s[buf][wm * 128 + mf * 16 + lm][rsw];
#pragma unroll
            for (int nf = 0; nf < 4; ++nf)
                acc[mf][nf] = mfma16(am, bfr[nf], acc[mf][nf]);
        }
        __builtin_amdgcn_s_setprio(0);
    };

    const int NT = Keff >> 5;                 // >= 8 in all launches
    issue(0); issue(1); issue(2);
    VMCNT(8);                                 // tile 0 landed; 1,2 in flight
    __builtin_amdgcn_s_barrier();
    __builtin_amdgcn_sched_barrier(0);

    for (int tt = 0; tt < NT - 3; ++tt) {
        issue(tt + 3);                        // buf((tt-1)&3): retired last iter
        compute(tt & 3);
        VMCNT(8);                             // t+1 landed; t+2,t+3 in flight
        __builtin_amdgcn_s_barrier();
        __builtin_amdgcn_sched_barrier(0);
    }
    compute((NT - 3) & 3);
    VMCNT(4);                                 // NT-2 landed; NT-1 in flight
    __builtin_amdgcn_s_barrier();
    __builtin_amdgcn_sched_barrier(0);
    compute((NT - 2) & 3);
    VMCNT(0);                                 // NT-1 landed (tail only)
    __builtin_amdgcn_s_barrier();
    __builtin_amdgcn_sched_barrier(0);
    compute((NT - 1) & 3);

    // ------------------------------------------------------------- epilogue
#pragma unroll
    for (int mf = 0; mf < 8; ++mf) {
#pragma unroll
        for (int nf = 0; nf < 4; ++nf) {
            const int row0 = mb + wm * 128 + mf * 16 + quad * 4;
            const int col = nb + wn * 64 + nf * 16 + lm;
            if (MODE == 0 && (col >> 10) == 2) {
                // v -> vT[b][h][dh][s]; 4 r-values are 4 consecutive s
                const int nn = col & 1023, h = nn >> 6, dh = nn & 63;
                const int b = row0 >> 10, s0 = row0 & 1023;
                const float bias = bias2[nn];
                half4v v4;
#pragma unroll
                for (int r = 0; r < 4; ++r) v4[r] = (_Float16)(acc[mf][nf][r] + bias);
                *(half4v*)&((_Float16*)outp2)[
                    (size_t)((b * NH + h) * DHEAD + dh) * SEQ + s0] = v4;
                continue;
            }
#pragma unroll
            for (int r = 0; r < 4; ++r) {
                float v = acc[mf][nf][r];
                const int row = row0 + r;
                if (MODE == 0) {
                    const int sel = col >> 10, nn = col & 1023;
                    v += (sel == 0 ? bias0 : bias1)[nn];
                    if (sel == 0) v *= 0.125f;     // DH^-0.5
                    ((_Float16*)outp)[(size_t)sel * MTOT * D_MODEL +
                                      (size_t)row * D_MODEL + nn] = (_Float16)v;
                } else if (MODE == 2) {
                    v = fmaxf(v + bias0[col], 0.f);
                    ((_Float16*)outp)[(size_t)row * N + col] = (_Float16)v;
                } else {   // MODE 3: raw f16 partial
                    ((_Float16*)outp)[(size_t)bz * M * N +
                                      (size_t)row * N + col] = (_Float16)v;
                }
            }
        }
    }
}

// ------------------------------------------------------------ flash attention
// block = (b,h) x 64 q-rows; wave w owns q-rows q0+w*16..+15, all keys.
__global__ __launch_bounds__(256) void attn_kernel(
        const _Float16* __restrict__ q, const _Float16* __restrict__ k,
        const _Float16* __restrict__ vT, _Float16* __restrict__ o,
        const float* __restrict__ mask) {
    const int b = blockIdx.y >> 4, h = blockIdx.y & 15;
    const int q0 = blockIdx.x * 64;
    const int t = threadIdx.x;
    const int wv = t >> 6, lane = t & 63, quad = lane >> 4, lm = lane & 15;

    __shared__ alignas(16) _Float16 k_s[512 * 8];
    __shared__ alignas(16) _Float16 v_s[512 * 8];
    __shared__ alignas(16) _Float16 p_s[4][16][72];

    const _Float16* kb = k + (size_t)b * SEQ * D_MODEL + h * 64;
    const _Float16* vb = vT + (size_t)(b * NH + h) * DHEAD * SEQ;
    int koff[2], voff[2];
#pragma unroll
    for (int jj = 0; jj < 2; ++jj) {
        const int c = t + jj * 256;
        const int row = c >> 3, gg = (c & 7) ^ (row & 7);
        koff[jj] = row * D_MODEL + gg * 8;
        voff[jj] = row * SEQ + gg * 8;
    }
    _Float16* kdst0 = k_s + (size_t)(wv * 64) * 8;
    _Float16* kdst1 = kdst0 + 256 * 8;
    _Float16* vdst0 = v_s + (size_t)(wv * 64) * 8;
    _Float16* vdst1 = vdst0 + 256 * 8;

    half8 qf[2];
    {
        const size_t qrow = (size_t)(b * SEQ + q0 + wv * 16 + lm);
#pragma unroll
        for (int ks = 0; ks < 2; ++ks)
            qf[ks] = *(const half8*)(q + qrow * D_MODEL + h * 64 + ks * 32 + quad * 8);
    }

    float l_part[4] = {0.f, 0.f, 0.f, 0.f};
    floatx4 Oacc[4];
#pragma unroll
    for (int nt = 0; nt < 4; ++nt) Oacc[nt] = (floatx4){0.f, 0.f, 0.f, 0.f};

    for (int jb = 0; jb < 16; ++jb) {
        const int kk0 = jb * 64;
        __syncthreads();
        gl_lds16(kb + kk0 * D_MODEL + koff[0], kdst0);
        gl_lds16(kb + kk0 * D_MODEL + koff[1], kdst1);
        gl_lds16(vb + kk0 + voff[0], vdst0);
        gl_lds16(vb + kk0 + voff[1], vdst1);
        __syncthreads();

        floatx4 sacc[4];
#pragma unroll
        for (int nt = 0; nt < 4; ++nt) {
            sacc[nt] = (floatx4){0.f, 0.f, 0.f, 0.f};
            const int row = nt * 16 + lm;
#pragma unroll
            for (int ks = 0; ks < 2; ++ks) {
                const int gg = (ks * 4 + quad) ^ (lm & 7);
                const half8 kf = *(const half8*)&k_s[row * 64 + gg * 8];
                sacc[nt] = mfma16(qf[ks], kf, sacc[nt]);
            }
        }
#pragma unroll
        for (int nt = 0; nt < 4; ++nt) {
            const float madd = (1.0f - mask[b * SEQ + kk0 + nt * 16 + lm]) * (-1.0e8f);
#pragma unroll
            for (int r = 0; r < 4; ++r) {
                const float p = __expf(sacc[nt][r] + madd);
                l_part[r] += p;
                p_s[wv][quad * 4 + r][nt * 16 + lm] = (_Float16)p;
            }
        }
#pragma unroll
        for (int ks = 0; ks < 2; ++ks) {
            const half8 pf = *(const half8*)&p_s[wv][lm][ks * 32 + quad * 8];
#pragma unroll
            for (int nt = 0; nt < 4; ++nt) {
                const int row = nt * 16 + lm;
                const int gg = (ks * 4 + quad) ^ (lm & 7);
                const half8 vf = *(const half8*)&v_s[row * 64 + gg * 8];
                Oacc[nt] = mfma16(pf, vf, Oacc[nt]);
            }
        }
    }
#pragma unroll
    for (int r = 0; r < 4; ++r) {
        float v = l_part[r];
#pragma unroll
        for (int off = 1; off < 16; off <<= 1) v += __shfl_xor(v, off, 64);
        l_part[r] = 1.0f / v;
    }
#pragma unroll
    for (int nt = 0; nt < 4; ++nt)
#pragma unroll
        for (int r = 0; r < 4; ++r) {
            const float v = Oacc[nt][r] * l_part[r];
            o[(size_t)(b * SEQ + q0 + wv * 16 + quad * 4 + r) * D_MODEL +
              h * 64 + nt * 16 + lm] = (_Float16)v;
        }
}

// --------------------------------------- residual + split-K reduce + bias + LN
template<int SPLIT>
__global__ __launch_bounds__(256) void ln_fused_kernel(
        const float* __restrict__ xf_in, const _Float16* __restrict__ part,
        const float* __restrict__ bias, const float* __restrict__ g,
        const float* __restrict__ bb, float* __restrict__ xo,
        _Float16* __restrict__ xh) {
    const int row = blockIdx.x, t = threadIdx.x;
    const int d0 = t * 4;
    const size_t base = (size_t)row * D_MODEL + d0;

    const float4 xv = *(const float4*)&xf_in[base];
    const float4 bv = *(const float4*)&bias[d0];
    float s[4] = {xv.x + bv.x, xv.y + bv.y, xv.z + bv.z, xv.w + bv.w};
#pragma unroll
    for (int p = 0; p < SPLIT; ++p) {
        const half4v pv = *(const half4v*)&part[(size_t)p * MTOT * D_MODEL + base];
#pragma unroll
        for (int i = 0; i < 4; ++i) s[i] += (float)pv[i];
    }
    float sum = s[0] + s[1] + s[2] + s[3];
    float sq = s[0]*s[0] + s[1]*s[1] + s[2]*s[2] + s[3]*s[3];
#pragma unroll
    for (int off = 1; off < 64; off <<= 1) {
        sum += __shfl_xor(sum, off, 64);
        sq  += __shfl_xor(sq, off, 64);
    }
    __shared__ float red[8];
    if ((t & 63) == 0) { red[(t >> 6) * 2] = sum; red[(t >> 6) * 2 + 1] = sq; }
    __syncthreads();
    sum = red[0] + red[2] + red[4] + red[6];
    sq  = red[1] + red[3] + red[5] + red[7];
    const float mean = sum * (1.0f / 1024.0f);
    const float var = sq * (1.0f / 1024.0f) - mean * mean;
    const float rstd = rsqrtf(var + 1e-5f);

    const float4 gv = *(const float4*)&g[d0];
    const float4 bbv = *(const float4*)&bb[d0];
    float o[4];
    o[0] = (s[0] - mean) * rstd * gv.x + bbv.x;
    o[1] = (s[1] - mean) * rstd * gv.y + bbv.y;
    o[2] = (s[2] - mean) * rstd * gv.z + bbv.z;
    o[3] = (s[3] - mean) * rstd * gv.w + bbv.w;
    *(float4*)&xo[base] = (float4){o[0], o[1], o[2], o[3]};
    half4v oh;
#pragma unroll
    for (int i = 0; i < 4; ++i) oh[i] = (_Float16)o[i];
    *(half4v*)&xh[base] = oh;
}

// ---------------------------------------------------------------------- host
extern "C" void kernel_launch(void* const* d_in, const int* in_sizes, int n_in,
                              void* d_out, int out_size, void* d_ws, size_t ws_size,
                              hipStream_t stream) {
    const float* x    = (const float*)d_in[0];
    const float* mask = (const float*)d_in[1];
    const float* Wq = (const float*)d_in[2];  const float* bq = (const float*)d_in[3];
    const float* Wk = (const float*)d_in[4];  const float* bk = (const float*)d_in[5];
    const float* Wv = (const float*)d_in[6];  const float* bv = (const float*)d_in[7];
    const float* Wo = (const float*)d_in[8];  const float* bo = (const float*)d_in[9];
    const float* W1 = (const float*)d_in[10]; const float* b1 = (const float*)d_in[11];
    const float* W2 = (const float*)d_in[12]; const float* b2 = (const float*)d_in[13];
    const float* lng = (const float*)d_in[14]; const float* lnb = (const float*)d_in[15];
    float* xf = (float*)d_out;

    char* w = (char*)d_ws;
    const size_t MB = 1048576;
    _Float16* xh    = (_Float16*)(w);                 // [0,8M)
    _Float16* qkv   = (_Float16*)(w + 8 * MB);        // [8M,32M)  q,k
    _Float16* oh    = (_Float16*)(w + 32 * MB);       // [32M,40M) attn out
    _Float16* part  = (_Float16*)(w + 40 * MB);       // [40M,72M) split-K partials (4x)
    _Float16* vT    = (_Float16*)(w + 40 * MB);       // aliases part (disjoint in time)
    _Float16* hh    = (_Float16*)(w + 72 * MB);       // [72M,104M) ffn hidden
    _Float16* wqkvT = (_Float16*)(w + 104 * MB);      // [104M,110M)
    _Float16* woT   = (_Float16*)(w + 110 * MB);      // [110M,112M)
    _Float16* w1T   = (_Float16*)(w + 8 * MB);        // aliases q (dead after attn)
    _Float16* w2T   = (_Float16*)(w + 16 * MB);       // aliases k (dead after attn)

    posenc_kernel<<<MTOT, 256, 0, stream>>>(x, xf, xh);

    for (int l = 0; l < NLAYER; ++l) {
        transpose_qkv_kernel<<<dim3(32, 32, 3), 256, 0, stream>>>(Wq, Wk, Wv, l, wqkvT);
        transpose_cvt_kernel<<<dim3(32, 32, 1), 256, 0, stream>>>(
            Wo + (size_t)l * 1048576, woT, 1024, 1024);

        gemm256_kernel<0, 1><<<dim3(12, 16), 512, 0, stream>>>(
            xh, wqkvT, bq + l * 1024, bk + l * 1024, bv + l * 1024,
            qkv, vT, MTOT, 3072, 1024);
        attn_kernel<<<dim3(16, 64), 256, 0, stream>>>(
            qkv, qkv + (size_t)MTOT * D_MODEL, vT, oh, mask);

        // q,k now dead -> stage W1^T/W2^T into their space
        transpose_cvt_kernel<<<dim3(128, 32, 1), 256, 0, stream>>>(
            W1 + (size_t)l * 4194304, w1T, 1024, 4096);
        transpose_cvt_kernel<<<dim3(32, 128, 1), 256, 0, stream>>>(
            W2 + (size_t)l * 4194304, w2T, 4096, 1024);

        gemm256_kernel<3, 4><<<dim3(4, 16, 4), 512, 0, stream>>>(
            oh, woT, nullptr, nullptr, nullptr, part, nullptr, MTOT, 1024, 1024);
        ln_fused_kernel<4><<<MTOT, 256, 0, stream>>>(
            xf, part, bo + l * 1024,
            lng + (size_t)(2 * l) * 1024, lnb + (size_t)(2 * l) * 1024, xf, xh);

        gemm256_kernel<2, 1><<<dim3(16, 16), 512, 0, stream>>>(
            xh, w1T, b1 + l * 4096, nullptr, nullptr, hh, nullptr, MTOT, 4096, 1024);
        gemm256_kernel<3, 4><<<dim3(4, 16, 4), 512, 0, stream>>>(
            hh, w2T, nullptr, nullptr, nullptr, part, nullptr, MTOT, 1024, 4096);
        ln_fused_kernel<4><<<MTOT, 256, 0, stream>>>(
            xf, part, b2 + l * 1024,
            lng + (size_t)(2 * l + 1) * 1024, lnb + (size_t)(2 * l + 1) * 1024,
            xf, xh);
    }
}